// Round 1
// baseline (155.432 us; speedup 1.0000x reference)
//
#include <hip/hip_runtime.h>
#include <hip/hip_bf16.h>
#include <stdint.h>

// Problem constants: T=512, B=32, I=512, H=512
#define T_DIM 512
#define B_DIM 32
#define K_DIM 512     // I
#define H_DIM 512
#define N_DIM 1536    // 3*H, gate-packed in h-pairs: n = (h>>1)*6 + (h&1)*3 + g
#define M_DIM 16384   // T*B

typedef __bf16 bf16_t;
typedef bf16_t bf16x8 __attribute__((ext_vector_type(8)));
typedef float floatx4 __attribute__((ext_vector_type(4)));

#define LOG2E 1.442695041f     // 1/ln(2)
#define TWO_LOG2E 2.885390082f

// ---------- fp32 -> bf16 (RNE), 8 elems/thread, both inputs fused ----------
// (unchanged from R-prev; W_ih rows permuted to h-pair gate packing)
__device__ __forceinline__ unsigned int f2bf_bits(float f) {
  uint32_t u = __builtin_bit_cast(uint32_t, f);
  u += 0x7FFFu + ((u >> 16) & 1u);
  return u >> 16;
}

__global__ void convert_both_kernel(const float* __restrict__ x,
                                    unsigned short* __restrict__ xb,
                                    const float* __restrict__ W,
                                    unsigned short* __restrict__ Wb) {
  int bid = blockIdx.x;
  const float* src;
  unsigned short* dst;
  int i;
  if (bid < 4096) {           // x: 8388608 elems, identity convert
    i = (bid * 256 + threadIdx.x) * 8;
    src = x + i;
    dst = xb + i;
  } else {                    // Wb: 1536 rows x 512, h-pair permuted
    i = ((bid - 4096) * 256 + threadIdx.x) * 8;
    int n = i >> 9;           // packed row
    int k = i & 511;
    int p6 = n / 6;
    int sub = n - p6 * 6;
    int hodd = (sub >= 3) ? 1 : 0;
    int g = sub - hodd * 3;
    int h = p6 * 2 + hodd;
    src = W + ((g << 9) + h) * 512 + k;
    dst = Wb + i;
  }
  const float4* p = (const float4*)src;
  float4 f0 = p[0];
  float4 f1 = p[1];
  uint4 v;
  v.x = f2bf_bits(f0.x) | (f2bf_bits(f0.y) << 16);
  v.y = f2bf_bits(f0.z) | (f2bf_bits(f0.w) << 16);
  v.z = f2bf_bits(f1.x) | (f2bf_bits(f1.y) << 16);
  v.w = f2bf_bits(f1.z) | (f2bf_bits(f1.w) << 16);
  *(uint4*)dst = v;
}

// ---------- bf16 GEMM: NT, 256x256 tile, BK=64, phase-split pipeline ----------
// R8: port of the 8-phase/counted-vmcnt schedule (T3+T4+T5). The previous
// 2-barrier structure (stage -> vmcnt(0) drain -> barrier -> MFMA) is the
// documented ~900TF/37%-MfmaUtil ceiling; counted vmcnt keeps prefetch loads
// in flight ACROSS barriers.
//   - 512 thr = 8 waves (2M x 4N), wave tile 128x64, acc[8][4] 16x16 frags.
//   - LDS 128KB: 2 buffers x (A 256x64 + B 256x64) bf16, 16B-chunk XOR
//     swizzle (src pre-swizzled, read swizzled -- both-sides, rule #21).
//   - Group t (4 phases = {kk x rowhalf}) computes K-tile t from buf[t&1].
//     Tile t+1's A halves issue in t's preamble, B halves in t's phase 1;
//     both land in buf[(t+1)&1] whose last reads completed before group t
//     started (phase barriers) -> DMA cannot overwrite live data.
//   - Group-boundary wait: vmcnt(4) (the 4 just-issued A loads stay in
//     flight; the blocking B loads were issued ~4 phases earlier). Only the
//     last group drains to 0, so the epilogue's LDS reuse sees no DMA.
__global__ __launch_bounds__(512, 2) void gemm_bf16_kernel(
    const unsigned short* __restrict__ A, const unsigned short* __restrict__ Bm,
    _Float16* __restrict__ C) {
  __shared__ bf16_t smem[65536];  // 128KB: buf b at b*32768 elems, [A 16384 | B 16384]
  const int tid = threadIdx.x;
  const int lane = tid & 63;
  const int w = tid >> 6;
  const int tileM = blockIdx.x * 256;
  const int tileN = blockIdx.y * 256;
  const int waveM = w >> 2;  // 0..1
  const int waveN = w & 3;   // 0..3
  const int lm = lane & 15;
  const int lg = lane >> 4;  // 0..3 k-chunk group

  floatx4 acc[8][4] = {};

  // stage one half-tile (128 rows x 64 cols bf16 = 16KB): 2 x global_load_lds
  // per thread. LDS dest linear in lane (wave-uniform base + lane*16); source
  // address carries the inverse swizzle.
  auto stage = [&](const unsigned short* __restrict__ G, int tileR, int kt,
                   int half, int bOfs) {
#pragma unroll
    for (int q = 0; q < 2; ++q) {
      int s = q * 512 + tid;
      int row = half * 128 + (s >> 3);
      int kc = (s & 7) ^ (row & 7);
      bf16_t* dst = smem + (kt & 1) * 32768 + bOfs + (half * 1024 + s) * 8;
      const unsigned short* gsrc =
          G + (size_t)(tileR + row) * K_DIM + kt * 64 + kc * 8;
      __builtin_amdgcn_global_load_lds(
          (const __attribute__((address_space(1))) unsigned int*)gsrc,
          (__attribute__((address_space(3))) unsigned int*)dst, 16, 0, 0);
    }
  };

  // prologue: K-tile 0 fully (A then B), 8 loads/thread
  stage(A, tileM, 0, 0, 0);
  stage(A, tileM, 0, 1, 0);
  stage(Bm, tileN, 0, 0, 16384);
  stage(Bm, tileN, 0, 1, 16384);

#pragma unroll
  for (int t = 0; t < 8; ++t) {
    const bf16_t* As = smem + (t & 1) * 32768;
    const bf16_t* Bs = As + 16384;
    // preamble: issue next tile's A halves, counted wait, align
    if (t + 1 < 8) {
      stage(A, tileM, t + 1, 0, 0);
      stage(A, tileM, t + 1, 1, 0);
      asm volatile("s_waitcnt vmcnt(4)" ::: "memory");
    } else {
      asm volatile("s_waitcnt vmcnt(0)" ::: "memory");  // drain before epilogue reuse
    }
    __builtin_amdgcn_s_barrier();

    bf16x8 bfr[4];
#pragma unroll
    for (int kk = 0; kk < 2; ++kk) {
#pragma unroll
      for (int rh = 0; rh < 2; ++rh) {
        bf16x8 afr[4];
        const int c = kk * 4 + lg;
#pragma unroll
        for (int i = 0; i < 4; ++i) {
          int row = waveM * 128 + (rh * 4 + i) * 16 + lm;
          afr[i] = *(const bf16x8*)(As + row * 64 + ((c ^ (row & 7)) << 3));
        }
        if (rh == 0) {
#pragma unroll
          for (int j = 0; j < 4; ++j) {
            int row = waveN * 64 + j * 16 + lm;
            bfr[j] = *(const bf16x8*)(Bs + row * 64 + ((c ^ (row & 7)) << 3));
          }
        }
        if (kk == 0 && rh == 0 && t + 1 < 8) {  // phase 1: issue next tile's B halves
          stage(Bm, tileN, t + 1, 0, 16384);
          stage(Bm, tileN, t + 1, 1, 16384);
        }
        __builtin_amdgcn_s_barrier();
        asm volatile("s_waitcnt lgkmcnt(0)" ::: "memory");
        __builtin_amdgcn_s_setprio(1);
#pragma unroll
        for (int i = 0; i < 4; ++i)
#pragma unroll
          for (int j = 0; j < 4; ++j)
            acc[rh * 4 + i][j] = __builtin_amdgcn_mfma_f32_16x16x32_bf16(
                afr[i], bfr[j], acc[rh * 4 + i][j], 0, 0, 0);
        __builtin_amdgcn_s_setprio(0);
        __builtin_amdgcn_s_barrier();
      }
    }
  }

  // Epilogue. MFMA C/D layout: col=lane&15 (+16j), row=(lane>>4)*4+reg (+16i).
  // 4 passes of 32 rows through a 4KB wave-private LDS region, read back as
  // 4-col quads -> 16 lanes x 8B = 128B contiguous stores. All vmcnt drained
  // (t=7 preamble) and all frag ds_reads done (phase barriers) before reuse.
  _Float16* ep = (_Float16*)smem + w * 2048;  // 32x64 fp16 per wave
  const int q = lm;            // col quad 0..15
  const int rgrp = lane >> 4;  // 0..3
  const size_t crow0 = (size_t)(tileM + waveM * 128);
  const int ccol = tileN + waveN * 64 + q * 4;
#pragma unroll
  for (int p = 0; p < 4; ++p) {
#pragma unroll
    for (int il = 0; il < 2; ++il) {
      const int i = 2 * p + il;
#pragma unroll
      for (int j = 0; j < 4; ++j) {
        const int cl = lm + j * 16;
        const int sub = (tileN + waveN * 64 + cl) % 6;
        const float scl = (sub == 2 || sub == 5) ? TWO_LOG2E : -LOG2E;
#pragma unroll
        for (int r = 0; r < 4; ++r) {
          int rl = (lane >> 4) * 4 + r + 16 * il;  // 0..31
          ep[rl * 64 + cl] = (_Float16)(scl * acc[i][j][r]);
        }
      }
    }
    // wave-private region: DS ops within a wave are ordered; no barrier
#pragma unroll
    for (int k = 0; k < 8; ++k) {
      int rl = rgrp + 4 * k;  // 0..31
      uint2 v = *(const uint2*)(ep + rl * 64 + q * 4);
      *(uint2*)(C + (crow0 + p * 32 + rl) * N_DIM + ccol) = v;
    }
  }
}

// ---------- diagonal GRU scan (unchanged) ----------
__global__ __launch_bounds__(64) void indgru_scan_kernel(
    const _Float16* __restrict__ gx, const float* __restrict__ h0,
    const float* __restrict__ w_hh, float* __restrict__ out,
    float* __restrict__ hlast) {
  const int idx = blockIdx.x * 64 + threadIdx.x;  // 0..16383
  const int b = idx >> 9;
  const int h = idx & (H_DIM - 1);
  const float wr = -LOG2E * w_hh[h];
  const float wz = -LOG2E * w_hh[H_DIM + h];
  const float wn = TWO_LOG2E * w_hh[2 * H_DIM + h];
  const int sh = (h & 1) << 4;  // funnel shift: 0 or 16 bits
  float hv = h0[idx];

  const char* base = (const char*)(gx + (size_t)b * N_DIM + (h >> 1) * 6) + ((h & 1) << 2);
  float* outp = out + (size_t)b * H_DIM + h;  // t-stride 16384 fp32

  constexpr int D = 32;
  constexpr size_t TSTRIDE = (size_t)B_DIM * N_DIM * sizeof(_Float16);  // 98304 B
  uint2 pq[D];
#pragma unroll
  for (int t = 0; t < D; ++t)
    pq[t] = *(const uint2*)(base + (size_t)t * TSTRIDE);

  auto cvt16 = [](uint32_t bits) {
    return (float)__builtin_bit_cast(_Float16, (unsigned short)bits);
  };

  for (int t0 = 0; t0 < T_DIM - D; t0 += D) {
#pragma unroll
    for (int s = 0; s < D; ++s) {
      const int t = t0 + s;
      uint2 qv = pq[s];
      pq[s] = *(const uint2*)(base + (size_t)(t + D) * TSTRIDE);
      asm volatile("" ::: "memory");  // pin prefetch distance
      uint64_t v = (((uint64_t)qv.y << 32) | qv.x) >> sh;
      float gr = cvt16((uint32_t)v);
      float gz = cvt16((uint32_t)(v >> 16));
      float gn = cvt16((uint32_t)(v >> 32));
      float ar = fmaf(wr, hv, gr);
      float az = fmaf(wz, hv, gz);
      float t1 = wn * hv;
      float er = __builtin_amdgcn_exp2f(ar);
      float ez = __builtin_amdgcn_exp2f(az);
      float r = __builtin_amdgcn_rcpf(1.0f + er);
      float z = __builtin_amdgcn_rcpf(1.0f + ez);
      float en = __builtin_amdgcn_exp2f(fmaf(r, t1, gn));
      float u = __builtin_amdgcn_rcpf(1.0f + en);
      float n = fmaf(-2.0f, u, 1.0f);
      float zh = z * hv;
      float omz = 1.0f - z;
      hv = fmaf(n, omz, zh);
      outp[(size_t)t * (B_DIM * H_DIM)] = hv;
    }
  }
#pragma unroll
  for (int s = 0; s < D; ++s) {
    const int t = T_DIM - D + s;
    uint2 qv = pq[s];
    uint64_t v = (((uint64_t)qv.y << 32) | qv.x) >> sh;
    float gr = cvt16((uint32_t)v);
    float gz = cvt16((uint32_t)(v >> 16));
    float gn = cvt16((uint32_t)(v >> 32));
    float ar = fmaf(wr, hv, gr);
    float az = fmaf(wz, hv, gz);
    float t1 = wn * hv;
    float er = __builtin_amdgcn_exp2f(ar);
    float ez = __builtin_amdgcn_exp2f(az);
    float r = __builtin_amdgcn_rcpf(1.0f + er);
    float z = __builtin_amdgcn_rcpf(1.0f + ez);
    float en = __builtin_amdgcn_exp2f(fmaf(r, t1, gn));
    float u = __builtin_amdgcn_rcpf(1.0f + en);
    float n = fmaf(-2.0f, u, 1.0f);
    float zh = z * hv;
    float omz = 1.0f - z;
    hv = fmaf(n, omz, zh);
    outp[(size_t)t * (B_DIM * H_DIM)] = hv;
  }
  hlast[idx] = hv;
}

extern "C" void kernel_launch(void* const* d_in, const int* in_sizes, int n_in,
                              void* d_out, int out_size, void* d_ws, size_t ws_size,
                              hipStream_t stream) {
  const float* x    = (const float*)d_in[0];   // (T,B,I)  = 8388608
  const float* h0   = (const float*)d_in[1];   // (B,H)    = 16384
  const float* W_ih = (const float*)d_in[2];   // (3H,I)   = 786432
  const float* w_hh = (const float*)d_in[3];   // (3,H)    = 1536

  float* out = (float*)d_out;                          // (T,B,H)
  float* hlast = out + (size_t)T_DIM * B_DIM * H_DIM;  // (1,B,H)

  // workspace: xb(bf16) 16 MB | Wb(bf16 1536x512) 1.5 MB | gx(fp16) 50 MB
  char* ws = (char*)d_ws;
  unsigned short* xb = (unsigned short*)ws;
  unsigned short* Wb = (unsigned short*)(ws + 16777216);
  _Float16* gx = (_Float16*)(ws + 16777216 + 1572864);

  convert_both_kernel<<<4480, 256, 0, stream>>>(x, xb, W_ih, Wb);

  dim3 grid(M_DIM / 256, N_DIM / 256);  // 64 x 6
  gemm_bf16_kernel<<<grid, 512, 0, stream>>>(xb, Wb, gx);

  indgru_scan_kernel<<<256, 64, 0, stream>>>(gx, h0, w_hh, out, hlast);
}